// Round 5
// baseline (706.882 us; speedup 1.0000x reference)
//
#include <hip/hip_runtime.h>
#include <hip/hip_bf16.h>
#include <math.h>

typedef unsigned short ushortT;
typedef __attribute__((ext_vector_type(8))) short short8;
typedef __attribute__((ext_vector_type(4))) short short4v;
typedef __attribute__((ext_vector_type(4))) float f32x4;
typedef __attribute__((ext_vector_type(4))) float float4v;

#define TOK 65536
#define NSEQ 4096
#define DIM 512

__device__ __forceinline__ float bf2f(ushortT u) {
  union { float f; unsigned int i; } v; v.i = ((unsigned int)u) << 16; return v.f;
}
__device__ __forceinline__ ushortT f2bf(float f) {
  union { float f; unsigned int i; } v; v.f = f;
  unsigned int r = v.i + 0x7fffu + ((v.i >> 16) & 1u);
  return (ushortT)(r >> 16);
}

// exact-grade GELU via A&S 7.1.26 erf (|err| ~1e-6)
__device__ __forceinline__ float fast_gelu(float x) {
  const float y = fabsf(x) * 0.70710678118654752f;
  const float t = __builtin_amdgcn_rcpf(__builtin_fmaf(0.3275911f, y, 1.f));
  float p = 1.061405429f;
  p = __builtin_fmaf(p, t, -1.453152027f);
  p = __builtin_fmaf(p, t, 1.421413741f);
  p = __builtin_fmaf(p, t, -0.284496736f);
  p = __builtin_fmaf(p, t, 0.254829592f);
  p = p * t;
  const float e = __builtin_amdgcn_exp2f(-y * y * 1.4426950408889634f);
  float erfv = __builtin_fmaf(-p, e, 1.f);
  erfv = copysignf(erfv, x);
  return 0.5f * x * (1.f + erfv);
}

#define GLOAD_LDS(gp, lp) __builtin_amdgcn_global_load_lds( \
    (const __attribute__((address_space(1))) unsigned int*)(gp), \
    (__attribute__((address_space(3))) unsigned int*)(lp), 16, 0, 0)

#define LGKM0 do { asm volatile("s_waitcnt lgkmcnt(0)" ::: "memory"); \
                   __builtin_amdgcn_sched_barrier(0); } while (0)
#define BAR __builtin_amdgcn_s_barrier()
#define VMC(n) asm volatile("s_waitcnt vmcnt(" #n ")" ::: "memory")
#define SB0 __builtin_amdgcn_sched_barrier(0)

// ---------------- weight f32 -> bf16 convert ----------------
__global__ void cvt_kernel(const float* __restrict__ in, ushortT* __restrict__ out, int n4) {
  int i = blockIdx.x * 256 + threadIdx.x;
  if (i >= n4) return;
  float4v v = *(const float4v*)(in + (size_t)i * 4);
  short4v o;
#pragma unroll
  for (int j = 0; j < 4; ++j) o[j] = (short)f2bf(v[j]);
  *(short4v*)(out + (size_t)i * 4) = o;
}

// ---------------- LayerNorm (one wave per token) ----------------
template <bool INBF>
__global__ __launch_bounds__(256)
void ln_kernel(const void* __restrict__ inp, const float* __restrict__ gw,
               const float* __restrict__ bw, ushortT* __restrict__ out)
{
  const int lane = threadIdx.x & 63;
  const size_t tok = (size_t)blockIdx.x * 4 + (threadIdx.x >> 6);
  const int col = lane * 8;
  float x[8];
  if constexpr (INBF) {
    short8 v = *(const short8*)((const ushortT*)inp + tok * DIM + col);
#pragma unroll
    for (int j = 0; j < 8; ++j) x[j] = bf2f((ushortT)v[j]);
  } else {
    const float* p = (const float*)inp + tok * DIM + col;
    float4v a = *(const float4v*)p, b = *(const float4v*)(p + 4);
#pragma unroll
    for (int j = 0; j < 4; ++j) { x[j] = a[j]; x[4 + j] = b[j]; }
  }
  float s = 0.f, ss = 0.f;
#pragma unroll
  for (int j = 0; j < 8; ++j) { s += x[j]; ss += x[j] * x[j]; }
#pragma unroll
  for (int off = 1; off < 64; off <<= 1) {
    s += __shfl_xor(s, off, 64);
    ss += __shfl_xor(ss, off, 64);
  }
  const float mean = s * (1.f / 512.f);
  const float var = ss * (1.f / 512.f) - mean * mean;
  const float rstd = rsqrtf(var + 1e-5f);
  float4v g1 = *(const float4v*)(gw + col), g2 = *(const float4v*)(gw + col + 4);
  float4v b1 = *(const float4v*)(bw + col), b2 = *(const float4v*)(bw + col + 4);
  short8 o;
#pragma unroll
  for (int j = 0; j < 4; ++j) {
    o[j]     = (short)f2bf((x[j]     - mean) * rstd * g1[j] + b1[j]);
    o[4 + j] = (short)f2bf((x[4 + j] - mean) * rstd * g2[j] + b2[j]);
  }
  *(short8*)(out + tok * DIM + col) = o;
}

// ---------------- 256x256 GEMM, even-read 4-phase schedule ----------------
// phases: (k0,m0): 8 reads | (k0,m1): 4 | (k1,m0): 8 | (k1,m1): 4  -- 16 MFMA each
// stage tile t+1 (8 loads) in ph0; vmcnt(0) at ph3 (issued ~3 phases earlier => free)
#define MFMA_PHASE(MH) \
  _Pragma("unroll") \
  for (int m_ = 0; m_ < 4; ++m_) \
    _Pragma("unroll") \
    for (int n_ = 0; n_ < 4; ++n_) \
      acc[(MH) * 4 + m_][n_] = __builtin_amdgcn_mfma_f32_16x16x32_bf16( \
          Af[m_], Bf[n_], acc[(MH) * 4 + m_][n_], 0, 0, 0)

#define STAGE_A2(bufp, h, gptr) do { \
    GLOAD_LDS((gptr) + (size_t)((h) * 128) * K,     (bufp) + (h) * 8192 + w * 1024); \
    GLOAD_LDS((gptr) + (size_t)((h) * 128 + 8) * K, (bufp) + (h) * 8192 + w * 1024 + 512); \
  } while (0)
#define STAGE_B2(bufp, h, gptr) do { \
    GLOAD_LDS((gptr) + (size_t)((h) * 128) * K,     (bufp) + (h) * 8192 + w * 1024); \
    GLOAD_LDS((gptr) + (size_t)((h) * 128 + 8) * K, (bufp) + (h) * 8192 + w * 1024 + 512); \
  } while (0)

template <int EPI>
__global__ __launch_bounds__(512, 2)
void gemm256(const ushortT* __restrict__ A, const ushortT* __restrict__ Bt,
             const float* __restrict__ bias, int M, int N, int K,
             ushortT* __restrict__ outb, float* __restrict__ outf,
             const float* __restrict__ resf, const ushortT* __restrict__ resb)
{
  __shared__ __align__(16) ushortT sm[65536];   // 128 KiB
  ushortT* const Ab0 = sm;
  ushortT* const Ab1 = sm + 16384;
  ushortT* const Bb0 = sm + 32768;
  ushortT* const Bb1 = sm + 49152;

  const int tid = threadIdx.x;
  const int w = tid >> 6, l = tid & 63;
  const int wr = w >> 2, wc = w & 3;

  // XCD-bijective swizzle
  const int nwg = gridDim.x * gridDim.y;
  int wg = blockIdx.y * gridDim.x + blockIdx.x;
  {
    const int q = nwg >> 3, r8 = nwg & 7;
    const int xc = wg & 7, yc = wg >> 3;
    wg = (xc < r8 ? xc * (q + 1) : r8 * (q + 1) + (xc - r8) * q) + yc;
  }
  const int nbn = N >> 8;
  const int mb = wg / nbn, nb = wg % nbn;
  const int m0 = mb << 8, n0 = nb << 8;
  const int NT = K >> 6;

  // staging source (per-lane, inverse-swizzled chunk)
  const ushortT* gA = A  + (size_t)(m0 + w * 16 + (l >> 3)) * K + (((l & 7) ^ (l >> 3)) << 3);
  const ushortT* gB = Bt + (size_t)(n0 + w * 16 + (l >> 3)) * K + (((l & 7) ^ (l >> 3)) << 3);

  // ds_read addressing (swizzled)
  const int rl = l & 15, ql = l >> 4;
  const int aoff = (wr * 128 + rl) * 64;
  const int boff = (wc * 64 + rl) * 64;
  const int cs0 = ((ql) ^ (l & 7)) << 3;       // k-slice 0 chunk
  const int cs1 = ((4 + ql) ^ (l & 7)) << 3;   // k-slice 1 chunk

  f32x4 acc[8][4];
  const f32x4 zero = {0.f, 0.f, 0.f, 0.f};
#pragma unroll
  for (int i = 0; i < 8; ++i)
#pragma unroll
    for (int j = 0; j < 4; ++j) acc[i][j] = zero;

  ushortT* Ac = Ab0; ushortT* An = Ab1;
  ushortT* Bc = Bb0; ushortT* Bn = Bb1;

  // prologue: tile 0 (8 loads), drain, publish
  STAGE_A2(Ac, 0, gA); STAGE_A2(Ac, 1, gA);
  STAGE_B2(Bc, 0, gB); STAGE_B2(Bc, 1, gB);
  VMC(0);
  BAR;

  short8 Af[4], Bf[4];
  size_t koff = 64;

  for (int t = 0; t < NT; ++t) {
    // ---- phase 0: (k0, m0) -- 8 reads + full tile-(t+1) stage ----
#pragma unroll
    for (int m = 0; m < 4; ++m) Af[m] = *(const short8*)(Ac + aoff + m * 1024 + cs0);
#pragma unroll
    for (int n = 0; n < 4; ++n) Bf[n] = *(const short8*)(Bc + boff + n * 1024 + cs0);
    if (t + 1 < NT) {
      STAGE_A2(An, 0, gA + koff); STAGE_A2(An, 1, gA + koff);
      STAGE_B2(Bn, 0, gB + koff); STAGE_B2(Bn, 1, gB + koff);
    }
    SB0; BAR; LGKM0;
    __builtin_amdgcn_s_setprio(1);
    MFMA_PHASE(0);
    __builtin_amdgcn_s_setprio(0);
    // ---- phase 1: (k0, m1) -- 4 reads ----
#pragma unroll
    for (int m = 0; m < 4; ++m) Af[m] = *(const short8*)(Ac + aoff + (4 + m) * 1024 + cs0);
    SB0; BAR; LGKM0;
    __builtin_amdgcn_s_setprio(1);
    MFMA_PHASE(1);
    __builtin_amdgcn_s_setprio(0);
    // ---- phase 2: (k1, m0) -- 8 reads ----
#pragma unroll
    for (int m = 0; m < 4; ++m) Af[m] = *(const short8*)(Ac + aoff + m * 1024 + cs1);
#pragma unroll
    for (int n = 0; n < 4; ++n) Bf[n] = *(const short8*)(Bc + boff + n * 1024 + cs1);
    SB0; BAR; LGKM0;
    __builtin_amdgcn_s_setprio(1);
    MFMA_PHASE(0);
    __builtin_amdgcn_s_setprio(0);
    // ---- phase 3: (k1, m1) -- 4 reads + buffer retire ----
#pragma unroll
    for (int m = 0; m < 4; ++m) Af[m] = *(const short8*)(Ac + aoff + (4 + m) * 1024 + cs1);
    SB0; BAR; LGKM0;
    __builtin_amdgcn_s_setprio(1);
    MFMA_PHASE(1);
    __builtin_amdgcn_s_setprio(0);
    if (t + 1 < NT) VMC(0);   // tile t+1 loads issued in ph0 (~3 phases ago) -> ~free
    BAR;                      // publish: next iter may read An/Bn and stage into Ac/Bc
    ushortT* tp;
    tp = Ac; Ac = An; An = tp;
    tp = Bc; Bc = Bn; Bn = tp;
    koff += 64;
  }

  // ---- epilogue ----
#pragma unroll
  for (int m = 0; m < 8; ++m) {
#pragma unroll
    for (int n = 0; n < 4; ++n) {
      const int col = n0 + wc * 64 + n * 16 + rl;
      const float bb = bias[col];
#pragma unroll
      for (int i = 0; i < 4; ++i) {
        const size_t row = (size_t)(m0 + wr * 128 + m * 16 + ql * 4 + i);
        float v = acc[m][n][i] + bb;
        if constexpr (EPI == 1) v += resf[row * (size_t)N + col];
        if constexpr (EPI == 2) v = fast_gelu(v);
        if constexpr (EPI == 3) {
          v += bf2f(resb[row * (size_t)N + col]);
          outf[row * (size_t)N + col] = v;
        } else {
          outb[row * (size_t)N + col] = f2bf(v);
        }
      }
    }
  }
}

// ---------------- windowed attention (one block/window, one wave/head) ----------------
__global__ __launch_bounds__(512)
void attn_kernel(const ushortT* __restrict__ qkv, ushortT* __restrict__ out)
{
  __shared__ __align__(16) ushortT sq[8][1544];
  const int wb = blockIdx.x;
  const int b  = wb >> 9;
  const int rr = wb & 511;
  const int w1 = rr >> 6;
  const int g  = rr & 63;
  const int tid = threadIdx.x;

#pragma unroll
  for (int c = 0; c < 3; ++c) {
    const int f = c * 512 + tid;
    const int i = f / 192;
    const int col = (f % 192) * 8;
    const int tin = (64 * g + 8 * i + w1 + 4) & (NSEQ - 1);
    const ushortT* src = qkv + ((size_t)b * NSEQ + tin) * 1536 + col;
    *(short8*)(&sq[i][col]) = *(const short8*)src;
  }
  __syncthreads();

  const int wave = tid >> 6, lane = tid & 63;
  const int h = wave;
  const int qi = lane >> 3, kj = lane & 7;

  float s = 0.f;
  const ushortT* qrow = &sq[qi][h * 64];
  const ushortT* krow = &sq[kj][512 + h * 64];
#pragma unroll
  for (int c = 0; c < 8; ++c) {
    short8 qa = *(const short8*)(qrow + c * 8);
    short8 ka = *(const short8*)(krow + c * 8);
#pragma unroll
    for (int j = 0; j < 8; ++j) s += bf2f((ushortT)qa[j]) * bf2f((ushortT)ka[j]);
  }
  s *= 0.125f;

  const int pq = 64 * g + 8 * qi + w1;
  const int pk = 64 * g + 8 * kj + w1;
  const int cq = (pq < 4088) ? 0 : (pq < 4092 ? 1 : 2);
  const int ck = (pk < 4088) ? 0 : (pk < 4092 ? 1 : 2);
  if (cq != ck) s -= 100.f;

  float mx = s;
  mx = fmaxf(mx, __shfl_xor(mx, 1, 64));
  mx = fmaxf(mx, __shfl_xor(mx, 2, 64));
  mx = fmaxf(mx, __shfl_xor(mx, 4, 64));
  const float e = expf(s - mx);
  float sum = e;
  sum += __shfl_xor(sum, 1, 64);
  sum += __shfl_xor(sum, 2, 64);
  sum += __shfl_xor(sum, 4, 64);
  const float p = e / sum;

  const int dc = lane & 7;
  float o[8];
#pragma unroll
  for (int j = 0; j < 8; ++j) o[j] = 0.f;
#pragma unroll
  for (int k2 = 0; k2 < 8; ++k2) {
    const float pk2 = __shfl(p, (lane & ~7) + k2, 64);
    short8 va = *(const short8*)(&sq[k2][1024 + h * 64 + dc * 8]);
#pragma unroll
    for (int j = 0; j < 8; ++j) o[j] += pk2 * bf2f((ushortT)va[j]);
  }

  const int tout = (512 * qi + 64 * w1 + g + 4) & (NSEQ - 1);
  short8 ov;
#pragma unroll
  for (int j = 0; j < 8; ++j) ov[j] = (short)f2bf(o[j]);
  *(short8*)(out + ((size_t)b * NSEQ + tout) * DIM + h * 64 + dc * 8) = ov;
}

// ---------------- host ----------------
extern "C" void kernel_launch(void* const* d_in, const int* in_sizes, int n_in,
                              void* d_out, int out_size, void* d_ws, size_t ws_size,
                              hipStream_t stream) {
  const float* x      = (const float*)d_in[0];
  const float* n1g    = (const float*)d_in[1];
  const float* n1b    = (const float*)d_in[2];
  const float* qkv_w  = (const float*)d_in[3];
  const float* qkv_b  = (const float*)d_in[4];
  const float* proj_w = (const float*)d_in[5];
  const float* proj_b = (const float*)d_in[6];
  const float* n2g    = (const float*)d_in[7];
  const float* n2b    = (const float*)d_in[8];
  const float* fc1_w  = (const float*)d_in[9];
  const float* fc1_b  = (const float*)d_in[10];
  const float* fc2_w  = (const float*)d_in[11];
  const float* fc2_b  = (const float*)d_in[12];
  float* out = (float*)d_out;

  size_t off = 0;
  char* ws = (char*)d_ws;
  auto alloc = [&](size_t b) { void* p = ws + off; off += (b + 255) & ~(size_t)255; return p; };

  ushortT* qkvw_b = (ushortT*)alloc((size_t)1536 * 512 * 2);
  ushortT* projw_b = (ushortT*)alloc((size_t)512 * 512 * 2);
  ushortT* fc1w_b = (ushortT*)alloc((size_t)2048 * 512 * 2);
  ushortT* fc2w_b = (ushortT*)alloc((size_t)512 * 2048 * 2);
  ushortT* bufA = (ushortT*)alloc((size_t)TOK * 512 * 2);    // xn -> attnout -> h_in
  ushortT* bufQ = (ushortT*)alloc((size_t)TOK * 1536 * 2);   // qkv ; then x1 (bf16)
  ushortT* x1 = bufQ;

  int nch = 1;
  while (nch < 16) {
    size_t need = (size_t)(TOK / nch) * 2048 * 2;
    if (off + need <= ws_size) break;
    nch <<= 1;
  }
  ushortT* h1 = (ushortT*)(ws + off);

  cvt_kernel<<<(1536 * 512 / 4 + 255) / 256, 256, 0, stream>>>(qkv_w, qkvw_b, 1536 * 512 / 4);
  cvt_kernel<<<(512 * 512 / 4 + 255) / 256, 256, 0, stream>>>(proj_w, projw_b, 512 * 512 / 4);
  cvt_kernel<<<(2048 * 512 / 4 + 255) / 256, 256, 0, stream>>>(fc1_w, fc1w_b, 2048 * 512 / 4);
  cvt_kernel<<<(512 * 2048 / 4 + 255) / 256, 256, 0, stream>>>(fc2_w, fc2w_b, 512 * 2048 / 4);

  ln_kernel<false><<<TOK / 4, 256, 0, stream>>>(x, n1g, n1b, bufA);

  gemm256<0><<<dim3(TOK / 256, 1536 / 256), 512, 0, stream>>>(
      bufA, qkvw_b, qkv_b, TOK, 1536, 512, bufQ, nullptr, nullptr, nullptr);

  attn_kernel<<<8192, 512, 0, stream>>>(bufQ, bufA);

  gemm256<1><<<dim3(TOK / 256, 512 / 256), 512, 0, stream>>>(
      bufA, projw_b, proj_b, TOK, 512, 512, x1, nullptr, x, nullptr);

  ln_kernel<true><<<TOK / 4, 256, 0, stream>>>(x1, n2g, n2b, bufA);

  const int tc = TOK / nch;
  for (int c = 0; c < nch; ++c) {
    const ushortT* hin = bufA + (size_t)c * tc * 512;
    gemm256<2><<<dim3(tc / 256, 2048 / 256), 512, 0, stream>>>(
        hin, fc1w_b, fc1_b, tc, 2048, 512, h1, nullptr, nullptr, nullptr);
    gemm256<3><<<dim3(tc / 256, 512 / 256), 512, 0, stream>>>(
        h1, fc2w_b, fc2_b, tc, 512, 2048, nullptr, out + (size_t)c * tc * 512,
        nullptr, x1 + (size_t)c * tc * 512);
  }
}

// Round 6
// 695.137 us; speedup vs baseline: 1.0169x; 1.0169x over previous
//
#include <hip/hip_runtime.h>
#include <hip/hip_bf16.h>
#include <math.h>

typedef unsigned short ushortT;
typedef __attribute__((ext_vector_type(8))) short short8;
typedef __attribute__((ext_vector_type(4))) short short4v;
typedef __attribute__((ext_vector_type(4))) float f32x4;
typedef __attribute__((ext_vector_type(4))) float float4v;

#define TOK 65536
#define NSEQ 4096
#define DIM 512

__device__ __forceinline__ float bf2f(ushortT u) {
  union { float f; unsigned int i; } v; v.i = ((unsigned int)u) << 16; return v.f;
}
__device__ __forceinline__ ushortT f2bf(float f) {
  union { float f; unsigned int i; } v; v.f = f;
  unsigned int r = v.i + 0x7fffu + ((v.i >> 16) & 1u);
  return (ushortT)(r >> 16);
}

// exact-grade GELU via A&S 7.1.26 erf (|err| ~1e-6)
__device__ __forceinline__ float fast_gelu(float x) {
  const float y = fabsf(x) * 0.70710678118654752f;
  const float t = __builtin_amdgcn_rcpf(__builtin_fmaf(0.3275911f, y, 1.f));
  float p = 1.061405429f;
  p = __builtin_fmaf(p, t, -1.453152027f);
  p = __builtin_fmaf(p, t, 1.421413741f);
  p = __builtin_fmaf(p, t, -0.284496736f);
  p = __builtin_fmaf(p, t, 0.254829592f);
  p = p * t;
  const float e = __builtin_amdgcn_exp2f(-y * y * 1.4426950408889634f);
  float erfv = __builtin_fmaf(-p, e, 1.f);
  erfv = copysignf(erfv, x);
  return 0.5f * x * (1.f + erfv);
}

#define GLOAD_LDS(gp, lp) __builtin_amdgcn_global_load_lds( \
    (const __attribute__((address_space(1))) unsigned int*)(gp), \
    (__attribute__((address_space(3))) unsigned int*)(lp), 16, 0, 0)

#define LGKM0 do { asm volatile("s_waitcnt lgkmcnt(0)" ::: "memory"); \
                   __builtin_amdgcn_sched_barrier(0); } while (0)
#define BAR __builtin_amdgcn_s_barrier()
#define VMC(n) asm volatile("s_waitcnt vmcnt(" #n ")" ::: "memory")
#define SB0 __builtin_amdgcn_sched_barrier(0)

// ---------------- weight f32 -> bf16 convert ----------------
__global__ void cvt_kernel(const float* __restrict__ in, ushortT* __restrict__ out, int n4) {
  int i = blockIdx.x * 256 + threadIdx.x;
  if (i >= n4) return;
  float4v v = *(const float4v*)(in + (size_t)i * 4);
  short4v o;
#pragma unroll
  for (int j = 0; j < 4; ++j) o[j] = (short)f2bf(v[j]);
  *(short4v*)(out + (size_t)i * 4) = o;
}

// ---------------- LayerNorm (one wave per token) ----------------
template <bool INBF>
__global__ __launch_bounds__(256)
void ln_kernel(const void* __restrict__ inp, const float* __restrict__ gw,
               const float* __restrict__ bw, ushortT* __restrict__ out)
{
  const int lane = threadIdx.x & 63;
  const size_t tok = (size_t)blockIdx.x * 4 + (threadIdx.x >> 6);
  const int col = lane * 8;
  float x[8];
  if constexpr (INBF) {
    short8 v = *(const short8*)((const ushortT*)inp + tok * DIM + col);
#pragma unroll
    for (int j = 0; j < 8; ++j) x[j] = bf2f((ushortT)v[j]);
  } else {
    const float* p = (const float*)inp + tok * DIM + col;
    float4v a = *(const float4v*)p, b = *(const float4v*)(p + 4);
#pragma unroll
    for (int j = 0; j < 4; ++j) { x[j] = a[j]; x[4 + j] = b[j]; }
  }
  float s = 0.f, ss = 0.f;
#pragma unroll
  for (int j = 0; j < 8; ++j) { s += x[j]; ss += x[j] * x[j]; }
#pragma unroll
  for (int off = 1; off < 64; off <<= 1) {
    s += __shfl_xor(s, off, 64);
    ss += __shfl_xor(ss, off, 64);
  }
  const float mean = s * (1.f / 512.f);
  const float var = ss * (1.f / 512.f) - mean * mean;
  const float rstd = rsqrtf(var + 1e-5f);
  float4v g1 = *(const float4v*)(gw + col), g2 = *(const float4v*)(gw + col + 4);
  float4v b1 = *(const float4v*)(bw + col), b2 = *(const float4v*)(bw + col + 4);
  short8 o;
#pragma unroll
  for (int j = 0; j < 4; ++j) {
    o[j]     = (short)f2bf((x[j]     - mean) * rstd * g1[j] + b1[j]);
    o[4 + j] = (short)f2bf((x[4 + j] - mean) * rstd * g2[j] + b2[j]);
  }
  *(short8*)(out + tok * DIM + col) = o;
}

// ---------------- 256x256 GEMM, even-read 4-phase schedule ----------------
#define MFMA_PHASE(MH) \
  _Pragma("unroll") \
  for (int m_ = 0; m_ < 4; ++m_) \
    _Pragma("unroll") \
    for (int n_ = 0; n_ < 4; ++n_) \
      acc[(MH) * 4 + m_][n_] = __builtin_amdgcn_mfma_f32_16x16x32_bf16( \
          Af[m_], Bf[n_], acc[(MH) * 4 + m_][n_], 0, 0, 0)

#define STAGE_A2(bufp, h, gptr) do { \
    GLOAD_LDS((gptr) + (size_t)((h) * 128) * K,     (bufp) + (h) * 8192 + w * 1024); \
    GLOAD_LDS((gptr) + (size_t)((h) * 128 + 8) * K, (bufp) + (h) * 8192 + w * 1024 + 512); \
  } while (0)
#define STAGE_B2(bufp, h, gptr) do { \
    GLOAD_LDS((gptr) + (size_t)((h) * 128) * K,     (bufp) + (h) * 8192 + w * 1024); \
    GLOAD_LDS((gptr) + (size_t)((h) * 128 + 8) * K, (bufp) + (h) * 8192 + w * 1024 + 512); \
  } while (0)

template <int EPI>
__global__ __launch_bounds__(512, 2)
void gemm256(const ushortT* __restrict__ A, const ushortT* __restrict__ Bt,
             const float* __restrict__ bias, int M, int N, int K,
             ushortT* __restrict__ outb, float* __restrict__ outf,
             const float* __restrict__ resf, const ushortT* __restrict__ resb)
{
  __shared__ __align__(16) ushortT sm[65536];   // 128 KiB
  ushortT* const Ab0 = sm;
  ushortT* const Ab1 = sm + 16384;
  ushortT* const Bb0 = sm + 32768;
  ushortT* const Bb1 = sm + 49152;

  const int tid = threadIdx.x;
  const int w = tid >> 6, l = tid & 63;
  const int wr = w >> 2, wc = w & 3;

  // XCD-bijective swizzle
  const int nwg = gridDim.x * gridDim.y;
  int wg = blockIdx.y * gridDim.x + blockIdx.x;
  {
    const int q = nwg >> 3, r8 = nwg & 7;
    const int xc = wg & 7, yc = wg >> 3;
    wg = (xc < r8 ? xc * (q + 1) : r8 * (q + 1) + (xc - r8) * q) + yc;
  }
  const int nbn = N >> 8;
  const int mb = wg / nbn, nb = wg % nbn;
  const int m0 = mb << 8, n0 = nb << 8;
  const int NT = K >> 6;

  // staging source (per-lane, inverse-swizzled chunk)
  const ushortT* gA = A  + (size_t)(m0 + w * 16 + (l >> 3)) * K + (((l & 7) ^ (l >> 3)) << 3);
  const ushortT* gB = Bt + (size_t)(n0 + w * 16 + (l >> 3)) * K + (((l & 7) ^ (l >> 3)) << 3);

  // ds_read addressing (swizzled)
  const int rl = l & 15, ql = l >> 4;
  const int aoff = (wr * 128 + rl) * 64;
  const int boff = (wc * 64 + rl) * 64;
  const int cs0 = ((ql) ^ (l & 7)) << 3;       // k-slice 0 chunk
  const int cs1 = ((4 + ql) ^ (l & 7)) << 3;   // k-slice 1 chunk

  f32x4 acc[8][4];
  const f32x4 zero = {0.f, 0.f, 0.f, 0.f};
#pragma unroll
  for (int i = 0; i < 8; ++i)
#pragma unroll
    for (int j = 0; j < 4; ++j) acc[i][j] = zero;

  ushortT* Ac = Ab0; ushortT* An = Ab1;
  ushortT* Bc = Bb0; ushortT* Bn = Bb1;

  // prologue: tile 0 (8 loads), drain, publish
  STAGE_A2(Ac, 0, gA); STAGE_A2(Ac, 1, gA);
  STAGE_B2(Bc, 0, gB); STAGE_B2(Bc, 1, gB);
  VMC(0);
  BAR;

  short8 Af[4], Bf[4];
  size_t koff = 64;

  for (int t = 0; t < NT; ++t) {
    // ---- phase 0: (k0, m0) -- 8 reads + full tile-(t+1) stage ----
#pragma unroll
    for (int m = 0; m < 4; ++m) Af[m] = *(const short8*)(Ac + aoff + m * 1024 + cs0);
#pragma unroll
    for (int n = 0; n < 4; ++n) Bf[n] = *(const short8*)(Bc + boff + n * 1024 + cs0);
    if (t + 1 < NT) {
      STAGE_A2(An, 0, gA + koff); STAGE_A2(An, 1, gA + koff);
      STAGE_B2(Bn, 0, gB + koff); STAGE_B2(Bn, 1, gB + koff);
    }
    SB0; BAR; LGKM0;
    __builtin_amdgcn_s_setprio(1);
    MFMA_PHASE(0);
    __builtin_amdgcn_s_setprio(0);
    // ---- phase 1: (k0, m1) -- 4 reads ----
#pragma unroll
    for (int m = 0; m < 4; ++m) Af[m] = *(const short8*)(Ac + aoff + (4 + m) * 1024 + cs0);
    SB0; BAR; LGKM0;
    __builtin_amdgcn_s_setprio(1);
    MFMA_PHASE(1);
    __builtin_amdgcn_s_setprio(0);
    // ---- phase 2: (k1, m0) -- 8 reads ----
#pragma unroll
    for (int m = 0; m < 4; ++m) Af[m] = *(const short8*)(Ac + aoff + m * 1024 + cs1);
#pragma unroll
    for (int n = 0; n < 4; ++n) Bf[n] = *(const short8*)(Bc + boff + n * 1024 + cs1);
    SB0; BAR; LGKM0;
    __builtin_amdgcn_s_setprio(1);
    MFMA_PHASE(0);
    __builtin_amdgcn_s_setprio(0);
    // ---- phase 3: (k1, m1) -- 4 reads + buffer retire ----
#pragma unroll
    for (int m = 0; m < 4; ++m) Af[m] = *(const short8*)(Ac + aoff + (4 + m) * 1024 + cs1);
    SB0; BAR; LGKM0;
    __builtin_amdgcn_s_setprio(1);
    MFMA_PHASE(1);
    __builtin_amdgcn_s_setprio(0);
    if (t + 1 < NT) VMC(0);
    BAR;
    ushortT* tp;
    tp = Ac; Ac = An; An = tp;
    tp = Bc; Bc = Bn; Bn = tp;
    koff += 64;
  }

  // ---- epilogue: LDS round-trip -> fully coalesced stores ----
  // Write side: acc[m][n] (4 rows x 1 col per lane) stored as one b128 at a
  // chunk address perm(c)=c^(c>>3) (bank spread, bijective). Read side: 4
  // column-chunks per lane re-assembled into row vectors by register
  // renaming (free transpose), then 16B/8B contiguous global stores.
  float* const ep = (float*)sm;   // 32768 f32 = 128 KiB
#pragma unroll
  for (int p = 0; p < 2; ++p) {
    if (p) BAR;                   // protect overwrite from pass-0 readers
    if (wr == p) {
#pragma unroll
      for (int m = 0; m < 8; ++m) {
#pragma unroll
        for (int n = 0; n < 4; ++n) {
          const int c = wc * 64 + n * 16 + rl;
          const int pc = c ^ (c >> 3);
          *(f32x4*)(ep + (m * 4 + ql) * 1024 + pc * 4) = acc[m][n];
        }
      }
    }
    BAR;
    // readback: wave w covers pages rb = w, w+8, w+16, w+24; lane covers cols 4l..4l+3
#pragma unroll
    for (int k = 0; k < 4; ++k) {
      const int rb = w + k * 8;                 // LDS page: holds rows 16*(rb>>2)+4*(rb&3)+i
      const int rowb = 16 * (rb >> 2) + 4 * (rb & 3);
      f32x4 rv[4];
#pragma unroll
      for (int j = 0; j < 4; ++j) {
        const int c = 4 * l + j;
        const int pc = c ^ (c >> 3);
        rv[j] = *(const f32x4*)(ep + rb * 1024 + pc * 4);
      }
      const int col = n0 + 4 * l;
      const float4v bb = *(const float4v*)(bias + col);
#pragma unroll
      for (int i = 0; i < 4; ++i) {
        const size_t row = (size_t)(m0 + p * 128 + rowb + i);
        float v0 = rv[0][i] + bb[0], v1 = rv[1][i] + bb[1],
              v2 = rv[2][i] + bb[2], v3 = rv[3][i] + bb[3];
        if constexpr (EPI == 1) {
          const float4v rr = *(const float4v*)(resf + row * (size_t)N + col);
          v0 += rr[0]; v1 += rr[1]; v2 += rr[2]; v3 += rr[3];
        }
        if constexpr (EPI == 2) {
          v0 = fast_gelu(v0); v1 = fast_gelu(v1); v2 = fast_gelu(v2); v3 = fast_gelu(v3);
        }
        if constexpr (EPI == 3) {
          const short4v rb4 = *(const short4v*)(resb + row * (size_t)N + col);
          v0 += bf2f((ushortT)rb4[0]); v1 += bf2f((ushortT)rb4[1]);
          v2 += bf2f((ushortT)rb4[2]); v3 += bf2f((ushortT)rb4[3]);
          float4v o = {v0, v1, v2, v3};
          *(float4v*)(outf + row * (size_t)N + col) = o;
        } else {
          short4v o;
          o[0] = (short)f2bf(v0); o[1] = (short)f2bf(v1);
          o[2] = (short)f2bf(v2); o[3] = (short)f2bf(v3);
          *(short4v*)(outb + row * (size_t)N + col) = o;
        }
      }
    }
  }
}

// ---------------- windowed attention (one block/window, one wave/head) ----------------
__global__ __launch_bounds__(512)
void attn_kernel(const ushortT* __restrict__ qkv, ushortT* __restrict__ out)
{
  __shared__ __align__(16) ushortT sq[8][1544];
  const int wb = blockIdx.x;
  const int b  = wb >> 9;
  const int rr = wb & 511;
  const int w1 = rr >> 6;
  const int g  = rr & 63;
  const int tid = threadIdx.x;

#pragma unroll
  for (int c = 0; c < 3; ++c) {
    const int f = c * 512 + tid;
    const int i = f / 192;
    const int col = (f % 192) * 8;
    const int tin = (64 * g + 8 * i + w1 + 4) & (NSEQ - 1);
    const ushortT* src = qkv + ((size_t)b * NSEQ + tin) * 1536 + col;
    *(short8*)(&sq[i][col]) = *(const short8*)src;
  }
  __syncthreads();

  const int wave = tid >> 6, lane = tid & 63;
  const int h = wave;
  const int qi = lane >> 3, kj = lane & 7;

  float s = 0.f;
  const ushortT* qrow = &sq[qi][h * 64];
  const ushortT* krow = &sq[kj][512 + h * 64];
#pragma unroll
  for (int c = 0; c < 8; ++c) {
    short8 qa = *(const short8*)(qrow + c * 8);
    short8 ka = *(const short8*)(krow + c * 8);
#pragma unroll
    for (int j = 0; j < 8; ++j) s += bf2f((ushortT)qa[j]) * bf2f((ushortT)ka[j]);
  }
  s *= 0.125f;

  const int pq = 64 * g + 8 * qi + w1;
  const int pk = 64 * g + 8 * kj + w1;
  const int cq = (pq < 4088) ? 0 : (pq < 4092 ? 1 : 2);
  const int ck = (pk < 4088) ? 0 : (pk < 4092 ? 1 : 2);
  if (cq != ck) s -= 100.f;

  float mx = s;
  mx = fmaxf(mx, __shfl_xor(mx, 1, 64));
  mx = fmaxf(mx, __shfl_xor(mx, 2, 64));
  mx = fmaxf(mx, __shfl_xor(mx, 4, 64));
  const float e = expf(s - mx);
  float sum = e;
  sum += __shfl_xor(sum, 1, 64);
  sum += __shfl_xor(sum, 2, 64);
  sum += __shfl_xor(sum, 4, 64);
  const float p = e / sum;

  const int dc = lane & 7;
  float o[8];
#pragma unroll
  for (int j = 0; j < 8; ++j) o[j] = 0.f;
#pragma unroll
  for (int k2 = 0; k2 < 8; ++k2) {
    const float pk2 = __shfl(p, (lane & ~7) + k2, 64);
    short8 va = *(const short8*)(&sq[k2][1024 + h * 64 + dc * 8]);
#pragma unroll
    for (int j = 0; j < 8; ++j) o[j] += pk2 * bf2f((ushortT)va[j]);
  }

  const int tout = (512 * qi + 64 * w1 + g + 4) & (NSEQ - 1);
  short8 ov;
#pragma unroll
  for (int j = 0; j < 8; ++j) ov[j] = (short)f2bf(o[j]);
  *(short8*)(out + ((size_t)b * NSEQ + tout) * DIM + h * 64 + dc * 8) = ov;
}

// ---------------- host ----------------
extern "C" void kernel_launch(void* const* d_in, const int* in_sizes, int n_in,
                              void* d_out, int out_size, void* d_ws, size_t ws_size,
                              hipStream_t stream) {
  const float* x      = (const float*)d_in[0];
  const float* n1g    = (const float*)d_in[1];
  const float* n1b    = (const float*)d_in[2];
  const float* qkv_w  = (const float*)d_in[3];
  const float* qkv_b  = (const float*)d_in[4];
  const float* proj_w = (const float*)d_in[5];
  const float* proj_b = (const float*)d_in[6];
  const float* n2g    = (const float*)d_in[7];
  const float* n2b    = (const float*)d_in[8];
  const float* fc1_w  = (const float*)d_in[9];
  const float* fc1_b  = (const float*)d_in[10];
  const float* fc2_w  = (const float*)d_in[11];
  const float* fc2_b  = (const float*)d_in[12];
  float* out = (float*)d_out;

  size_t off = 0;
  char* ws = (char*)d_ws;
  auto alloc = [&](size_t b) { void* p = ws + off; off += (b + 255) & ~(size_t)255; return p; };

  ushortT* qkvw_b = (ushortT*)alloc((size_t)1536 * 512 * 2);
  ushortT* projw_b = (ushortT*)alloc((size_t)512 * 512 * 2);
  ushortT* fc1w_b = (ushortT*)alloc((size_t)2048 * 512 * 2);
  ushortT* fc2w_b = (ushortT*)alloc((size_t)512 * 2048 * 2);
  ushortT* bufA = (ushortT*)alloc((size_t)TOK * 512 * 2);    // xn -> attnout -> h_in
  ushortT* bufQ = (ushortT*)alloc((size_t)TOK * 1536 * 2);   // qkv ; then x1 (bf16)
  ushortT* x1 = bufQ;

  int nch = 1;
  while (nch < 16) {
    size_t need = (size_t)(TOK / nch) * 2048 * 2;
    if (off + need <= ws_size) break;
    nch <<= 1;
  }
  ushortT* h1 = (ushortT*)(ws + off);

  cvt_kernel<<<(1536 * 512 / 4 + 255) / 256, 256, 0, stream>>>(qkv_w, qkvw_b, 1536 * 512 / 4);
  cvt_kernel<<<(512 * 512 / 4 + 255) / 256, 256, 0, stream>>>(proj_w, projw_b, 512 * 512 / 4);
  cvt_kernel<<<(2048 * 512 / 4 + 255) / 256, 256, 0, stream>>>(fc1_w, fc1w_b, 2048 * 512 / 4);
  cvt_kernel<<<(512 * 2048 / 4 + 255) / 256, 256, 0, stream>>>(fc2_w, fc2w_b, 512 * 2048 / 4);

  ln_kernel<false><<<TOK / 4, 256, 0, stream>>>(x, n1g, n1b, bufA);

  gemm256<0><<<dim3(TOK / 256, 1536 / 256), 512, 0, stream>>>(
      bufA, qkvw_b, qkv_b, TOK, 1536, 512, bufQ, nullptr, nullptr, nullptr);

  attn_kernel<<<8192, 512, 0, stream>>>(bufQ, bufA);

  gemm256<1><<<dim3(TOK / 256, 512 / 256), 512, 0, stream>>>(
      bufA, projw_b, proj_b, TOK, 512, 512, x1, nullptr, x, nullptr);

  ln_kernel<true><<<TOK / 4, 256, 0, stream>>>(x1, n2g, n2b, bufA);

  const int tc = TOK / nch;
  for (int c = 0; c < nch; ++c) {
    const ushortT* hin = bufA + (size_t)c * tc * 512;
    gemm256<2><<<dim3(tc / 256, 2048 / 256), 512, 0, stream>>>(
        hin, fc1w_b, fc1_b, tc, 2048, 512, h1, nullptr, nullptr, nullptr);
    gemm256<3><<<dim3(tc / 256, 512 / 256), 512, 0, stream>>>(
        h1, fc2w_b, fc2_b, tc, 512, 2048, nullptr, out + (size_t)c * tc * 512,
        nullptr, x1 + (size_t)c * tc * 512);
  }
}

// Round 7
// 681.010 us; speedup vs baseline: 1.0380x; 1.0207x over previous
//
#include <hip/hip_runtime.h>
#include <hip/hip_bf16.h>
#include <math.h>

typedef unsigned short ushortT;
typedef __attribute__((ext_vector_type(8))) short short8;
typedef __attribute__((ext_vector_type(4))) short short4v;
typedef __attribute__((ext_vector_type(4))) float f32x4;
typedef __attribute__((ext_vector_type(4))) float float4v;

#define TOK 65536
#define NSEQ 4096
#define DIM 512

__device__ __forceinline__ float bf2f(ushortT u) {
  union { float f; unsigned int i; } v; v.i = ((unsigned int)u) << 16; return v.f;
}
__device__ __forceinline__ ushortT f2bf(float f) {
  union { float f; unsigned int i; } v; v.f = f;
  unsigned int r = v.i + 0x7fffu + ((v.i >> 16) & 1u);
  return (ushortT)(r >> 16);
}

// exact-grade GELU via A&S 7.1.26 erf (|err| ~1e-6)
__device__ __forceinline__ float fast_gelu(float x) {
  const float y = fabsf(x) * 0.70710678118654752f;
  const float t = __builtin_amdgcn_rcpf(__builtin_fmaf(0.3275911f, y, 1.f));
  float p = 1.061405429f;
  p = __builtin_fmaf(p, t, -1.453152027f);
  p = __builtin_fmaf(p, t, 1.421413741f);
  p = __builtin_fmaf(p, t, -0.284496736f);
  p = __builtin_fmaf(p, t, 0.254829592f);
  p = p * t;
  const float e = __builtin_amdgcn_exp2f(-y * y * 1.4426950408889634f);
  float erfv = __builtin_fmaf(-p, e, 1.f);
  erfv = copysignf(erfv, x);
  return 0.5f * x * (1.f + erfv);
}

#define GLOAD_LDS(gp, lp) __builtin_amdgcn_global_load_lds( \
    (const __attribute__((address_space(1))) unsigned int*)(gp), \
    (__attribute__((address_space(3))) unsigned int*)(lp), 16, 0, 0)

#define BAR __builtin_amdgcn_s_barrier()
#define VMC(n) asm volatile("s_waitcnt vmcnt(" #n ")" ::: "memory")
#define SB0 __builtin_amdgcn_sched_barrier(0)

// ---------------- weight f32 -> bf16 convert ----------------
__global__ void cvt_kernel(const float* __restrict__ in, ushortT* __restrict__ out, int n4) {
  int i = blockIdx.x * 256 + threadIdx.x;
  if (i >= n4) return;
  float4v v = *(const float4v*)(in + (size_t)i * 4);
  short4v o;
#pragma unroll
  for (int j = 0; j < 4; ++j) o[j] = (short)f2bf(v[j]);
  *(short4v*)(out + (size_t)i * 4) = o;
}

// ---------------- LayerNorm (one wave per token) ----------------
template <bool INBF>
__global__ __launch_bounds__(256)
void ln_kernel(const void* __restrict__ inp, const float* __restrict__ gw,
               const float* __restrict__ bw, ushortT* __restrict__ out)
{
  const int lane = threadIdx.x & 63;
  const size_t tok = (size_t)blockIdx.x * 4 + (threadIdx.x >> 6);
  const int col = lane * 8;
  float x[8];
  if constexpr (INBF) {
    short8 v = *(const short8*)((const ushortT*)inp + tok * DIM + col);
#pragma unroll
    for (int j = 0; j < 8; ++j) x[j] = bf2f((ushortT)v[j]);
  } else {
    const float* p = (const float*)inp + tok * DIM + col;
    float4v a = *(const float4v*)p, b = *(const float4v*)(p + 4);
#pragma unroll
    for (int j = 0; j < 4; ++j) { x[j] = a[j]; x[4 + j] = b[j]; }
  }
  float s = 0.f, ss = 0.f;
#pragma unroll
  for (int j = 0; j < 8; ++j) { s += x[j]; ss += x[j] * x[j]; }
#pragma unroll
  for (int off = 1; off < 64; off <<= 1) {
    s += __shfl_xor(s, off, 64);
    ss += __shfl_xor(ss, off, 64);
  }
  const float mean = s * (1.f / 512.f);
  const float var = ss * (1.f / 512.f) - mean * mean;
  const float rstd = rsqrtf(var + 1e-5f);
  float4v g1 = *(const float4v*)(gw + col), g2 = *(const float4v*)(gw + col + 4);
  float4v b1 = *(const float4v*)(bw + col), b2 = *(const float4v*)(bw + col + 4);
  short8 o;
#pragma unroll
  for (int j = 0; j < 4; ++j) {
    o[j]     = (short)f2bf((x[j]     - mean) * rstd * g1[j] + b1[j]);
    o[4 + j] = (short)f2bf((x[4 + j] - mean) * rstd * g2[j] + b2[j]);
  }
  *(short8*)(out + tok * DIM + col) = o;
}

// ---------------- 256x256 GEMM, barrier-free K-tile body ----------------
// Per K-tile: {stage 8 loads for t+1 | 24 ds_read_b128 | 64 MFMA} with NO
// intra-tile barriers -- compiler software-pipelines (fine-grained lgkmcnt),
// waves skew freely (2/SIMD). Only sync: VMC(0)+BAR at the tile boundary
// (publishes staged t+1 buffer; all reads of retiring buffer done by then
// since each wave's MFMAs force its own lgkm drain before it reaches BAR).
#define MFMA_PHASE(MH) \
  _Pragma("unroll") \
  for (int m_ = 0; m_ < 4; ++m_) \
    _Pragma("unroll") \
    for (int n_ = 0; n_ < 4; ++n_) \
      acc[(MH) * 4 + m_][n_] = __builtin_amdgcn_mfma_f32_16x16x32_bf16( \
          Af[m_], Bf[n_], acc[(MH) * 4 + m_][n_], 0, 0, 0)

#define STAGE_A2(bufp, h, gptr) do { \
    GLOAD_LDS((gptr) + (size_t)((h) * 128) * K,     (bufp) + (h) * 8192 + w * 1024); \
    GLOAD_LDS((gptr) + (size_t)((h) * 128 + 8) * K, (bufp) + (h) * 8192 + w * 1024 + 512); \
  } while (0)
#define STAGE_B2(bufp, h, gptr) do { \
    GLOAD_LDS((gptr) + (size_t)((h) * 128) * K,     (bufp) + (h) * 8192 + w * 1024); \
    GLOAD_LDS((gptr) + (size_t)((h) * 128 + 8) * K, (bufp) + (h) * 8192 + w * 1024 + 512); \
  } while (0)

template <int EPI>
__global__ __launch_bounds__(512, 2)
void gemm256(const ushortT* __restrict__ A, const ushortT* __restrict__ Bt,
             const float* __restrict__ bias, int M, int N, int K,
             ushortT* __restrict__ outb, float* __restrict__ outf,
             const float* __restrict__ resf, const ushortT* __restrict__ resb)
{
  __shared__ __align__(16) ushortT sm[65536];   // 128 KiB
  ushortT* const Ab0 = sm;
  ushortT* const Ab1 = sm + 16384;
  ushortT* const Bb0 = sm + 32768;
  ushortT* const Bb1 = sm + 49152;

  const int tid = threadIdx.x;
  const int w = tid >> 6, l = tid & 63;
  const int wr = w >> 2, wc = w & 3;

  // XCD-bijective swizzle
  const int nwg = gridDim.x * gridDim.y;
  int wg = blockIdx.y * gridDim.x + blockIdx.x;
  {
    const int q = nwg >> 3, r8 = nwg & 7;
    const int xc = wg & 7, yc = wg >> 3;
    wg = (xc < r8 ? xc * (q + 1) : r8 * (q + 1) + (xc - r8) * q) + yc;
  }
  const int nbn = N >> 8;
  const int mb = wg / nbn, nb = wg % nbn;
  const int m0 = mb << 8, n0 = nb << 8;
  const int NT = K >> 6;

  // staging source (per-lane, inverse-swizzled chunk)
  const ushortT* gA = A  + (size_t)(m0 + w * 16 + (l >> 3)) * K + (((l & 7) ^ (l >> 3)) << 3);
  const ushortT* gB = Bt + (size_t)(n0 + w * 16 + (l >> 3)) * K + (((l & 7) ^ (l >> 3)) << 3);

  // ds_read addressing (swizzled)
  const int rl = l & 15, ql = l >> 4;
  const int aoff = (wr * 128 + rl) * 64;
  const int boff = (wc * 64 + rl) * 64;
  const int cs0 = ((ql) ^ (l & 7)) << 3;       // k-slice 0 chunk
  const int cs1 = ((4 + ql) ^ (l & 7)) << 3;   // k-slice 1 chunk

  f32x4 acc[8][4];
  const f32x4 zero = {0.f, 0.f, 0.f, 0.f};
#pragma unroll
  for (int i = 0; i < 8; ++i)
#pragma unroll
    for (int j = 0; j < 4; ++j) acc[i][j] = zero;

  ushortT* Ac = Ab0; ushortT* An = Ab1;
  ushortT* Bc = Bb0; ushortT* Bn = Bb1;

  // prologue: tile 0 (8 loads), drain, publish
  STAGE_A2(Ac, 0, gA); STAGE_A2(Ac, 1, gA);
  STAGE_B2(Bc, 0, gB); STAGE_B2(Bc, 1, gB);
  VMC(0);
  BAR;
  SB0;

  short8 Af[4], Bf[4];
  size_t koff = 64;

  for (int t = 0; t < NT; ++t) {
    // stage tile t+1 early (max vmem slack)
    if (t + 1 < NT) {
      STAGE_A2(An, 0, gA + koff); STAGE_A2(An, 1, gA + koff);
      STAGE_B2(Bn, 0, gB + koff); STAGE_B2(Bn, 1, gB + koff);
    }
    // ---- k-slice 0, m-half 0 ----
#pragma unroll
    for (int m = 0; m < 4; ++m) Af[m] = *(const short8*)(Ac + aoff + m * 1024 + cs0);
#pragma unroll
    for (int n = 0; n < 4; ++n) Bf[n] = *(const short8*)(Bc + boff + n * 1024 + cs0);
    MFMA_PHASE(0);
    // ---- k-slice 0, m-half 1 ----
#pragma unroll
    for (int m = 0; m < 4; ++m) Af[m] = *(const short8*)(Ac + aoff + (4 + m) * 1024 + cs0);
    MFMA_PHASE(1);
    // ---- k-slice 1, m-half 0 ----
#pragma unroll
    for (int m = 0; m < 4; ++m) Af[m] = *(const short8*)(Ac + aoff + m * 1024 + cs1);
#pragma unroll
    for (int n = 0; n < 4; ++n) Bf[n] = *(const short8*)(Bc + boff + n * 1024 + cs1);
    MFMA_PHASE(0);
    // ---- k-slice 1, m-half 1 ----
#pragma unroll
    for (int m = 0; m < 4; ++m) Af[m] = *(const short8*)(Ac + aoff + (4 + m) * 1024 + cs1);
    MFMA_PHASE(1);
    // ---- boundary: publish t+1, retire current ----
    if (t + 1 < NT) VMC(0);
    BAR;
    SB0;
    ushortT* tp;
    tp = Ac; Ac = An; An = tp;
    tp = Bc; Bc = Bn; Bn = tp;
    koff += 64;
  }

  // ---- epilogue: LDS round-trip -> fully coalesced stores ----
  float* const ep = (float*)sm;   // 32768 f32 = 128 KiB
#pragma unroll
  for (int p = 0; p < 2; ++p) {
    if (p) BAR;                   // protect overwrite from pass-0 readers
    if (wr == p) {
#pragma unroll
      for (int m = 0; m < 8; ++m) {
#pragma unroll
        for (int n = 0; n < 4; ++n) {
          const int c = wc * 64 + n * 16 + rl;
          const int pc = c ^ (c >> 3);
          *(f32x4*)(ep + (m * 4 + ql) * 1024 + pc * 4) = acc[m][n];
        }
      }
    }
    BAR;
#pragma unroll
    for (int k = 0; k < 4; ++k) {
      const int rb = w + k * 8;
      const int rowb = 16 * (rb >> 2) + 4 * (rb & 3);
      f32x4 rv[4];
#pragma unroll
      for (int j = 0; j < 4; ++j) {
        const int c = 4 * l + j;
        const int pc = c ^ (c >> 3);
        rv[j] = *(const f32x4*)(ep + rb * 1024 + pc * 4);
      }
      const int col = n0 + 4 * l;
      const float4v bb = *(const float4v*)(bias + col);
#pragma unroll
      for (int i = 0; i < 4; ++i) {
        const size_t row = (size_t)(m0 + p * 128 + rowb + i);
        float v0 = rv[0][i] + bb[0], v1 = rv[1][i] + bb[1],
              v2 = rv[2][i] + bb[2], v3 = rv[3][i] + bb[3];
        if constexpr (EPI == 1) {
          const float4v rr = *(const float4v*)(resf + row * (size_t)N + col);
          v0 += rr[0]; v1 += rr[1]; v2 += rr[2]; v3 += rr[3];
        }
        if constexpr (EPI == 2) {
          v0 = fast_gelu(v0); v1 = fast_gelu(v1); v2 = fast_gelu(v2); v3 = fast_gelu(v3);
        }
        if constexpr (EPI == 3) {
          const short4v rb4 = *(const short4v*)(resb + row * (size_t)N + col);
          v0 += bf2f((ushortT)rb4[0]); v1 += bf2f((ushortT)rb4[1]);
          v2 += bf2f((ushortT)rb4[2]); v3 += bf2f((ushortT)rb4[3]);
          float4v o = {v0, v1, v2, v3};
          *(float4v*)(outf + row * (size_t)N + col) = o;
        } else {
          short4v o;
          o[0] = (short)f2bf(v0); o[1] = (short)f2bf(v1);
          o[2] = (short)f2bf(v2); o[3] = (short)f2bf(v3);
          *(short4v*)(outb + row * (size_t)N + col) = o;
        }
      }
    }
  }
}

// ---------------- windowed attention (one block/window, one wave/head) ----------------
__global__ __launch_bounds__(512)
void attn_kernel(const ushortT* __restrict__ qkv, ushortT* __restrict__ out)
{
  __shared__ __align__(16) ushortT sq[8][1544];
  const int wb = blockIdx.x;
  const int b  = wb >> 9;
  const int rr = wb & 511;
  const int w1 = rr >> 6;
  const int g  = rr & 63;
  const int tid = threadIdx.x;

#pragma unroll
  for (int c = 0; c < 3; ++c) {
    const int f = c * 512 + tid;
    const int i = f / 192;
    const int col = (f % 192) * 8;
    const int tin = (64 * g + 8 * i + w1 + 4) & (NSEQ - 1);
    const ushortT* src = qkv + ((size_t)b * NSEQ + tin) * 1536 + col;
    *(short8*)(&sq[i][col]) = *(const short8*)src;
  }
  __syncthreads();

  const int wave = tid >> 6, lane = tid & 63;
  const int h = wave;
  const int qi = lane >> 3, kj = lane & 7;

  float s = 0.f;
  const ushortT* qrow = &sq[qi][h * 64];
  const ushortT* krow = &sq[kj][512 + h * 64];
#pragma unroll
  for (int c = 0; c < 8; ++c) {
    short8 qa = *(const short8*)(qrow + c * 8);
    short8 ka = *(const short8*)(krow + c * 8);
#pragma unroll
    for (int j = 0; j < 8; ++j) s += bf2f((ushortT)qa[j]) * bf2f((ushortT)ka[j]);
  }
  s *= 0.125f;

  const int pq = 64 * g + 8 * qi + w1;
  const int pk = 64 * g + 8 * kj + w1;
  const int cq = (pq < 4088) ? 0 : (pq < 4092 ? 1 : 2);
  const int ck = (pk < 4088) ? 0 : (pk < 4092 ? 1 : 2);
  if (cq != ck) s -= 100.f;

  float mx = s;
  mx = fmaxf(mx, __shfl_xor(mx, 1, 64));
  mx = fmaxf(mx, __shfl_xor(mx, 2, 64));
  mx = fmaxf(mx, __shfl_xor(mx, 4, 64));
  const float e = expf(s - mx);
  float sum = e;
  sum += __shfl_xor(sum, 1, 64);
  sum += __shfl_xor(sum, 2, 64);
  sum += __shfl_xor(sum, 4, 64);
  const float p = e / sum;

  const int dc = lane & 7;
  float o[8];
#pragma unroll
  for (int j = 0; j < 8; ++j) o[j] = 0.f;
#pragma unroll
  for (int k2 = 0; k2 < 8; ++k2) {
    const float pk2 = __shfl(p, (lane & ~7) + k2, 64);
    short8 va = *(const short8*)(&sq[k2][1024 + h * 64 + dc * 8]);
#pragma unroll
    for (int j = 0; j < 8; ++j) o[j] += pk2 * bf2f((ushortT)va[j]);
  }

  const int tout = (512 * qi + 64 * w1 + g + 4) & (NSEQ - 1);
  short8 ov;
#pragma unroll
  for (int j = 0; j < 8; ++j) ov[j] = (short)f2bf(o[j]);
  *(short8*)(out + ((size_t)b * NSEQ + tout) * DIM + h * 64 + dc * 8) = ov;
}

// ---------------- host ----------------
extern "C" void kernel_launch(void* const* d_in, const int* in_sizes, int n_in,
                              void* d_out, int out_size, void* d_ws, size_t ws_size,
                              hipStream_t stream) {
  const float* x      = (const float*)d_in[0];
  const float* n1g    = (const float*)d_in[1];
  const float* n1b    = (const float*)d_in[2];
  const float* qkv_w  = (const float*)d_in[3];
  const float* qkv_b  = (const float*)d_in[4];
  const float* proj_w = (const float*)d_in[5];
  const float* proj_b = (const float*)d_in[6];
  const float* n2g    = (const float*)d_in[7];
  const float* n2b    = (const float*)d_in[8];
  const float* fc1_w  = (const float*)d_in[9];
  const float* fc1_b  = (const float*)d_in[10];
  const float* fc2_w  = (const float*)d_in[11];
  const float* fc2_b  = (const float*)d_in[12];
  float* out = (float*)d_out;

  size_t off = 0;
  char* ws = (char*)d_ws;
  auto alloc = [&](size_t b) { void* p = ws + off; off += (b + 255) & ~(size_t)255; return p; };

  ushortT* qkvw_b = (ushortT*)alloc((size_t)1536 * 512 * 2);
  ushortT* projw_b = (ushortT*)alloc((size_t)512 * 512 * 2);
  ushortT* fc1w_b = (ushortT*)alloc((size_t)2048 * 512 * 2);
  ushortT* fc2w_b = (ushortT*)alloc((size_t)512 * 2048 * 2);
  ushortT* bufA = (ushortT*)alloc((size_t)TOK * 512 * 2);    // xn -> attnout -> h_in
  ushortT* bufQ = (ushortT*)alloc((size_t)TOK * 1536 * 2);   // qkv ; then x1 (bf16)
  ushortT* x1 = bufQ;

  int nch = 1;
  while (nch < 16) {
    size_t need = (size_t)(TOK / nch) * 2048 * 2;
    if (off + need <= ws_size) break;
    nch <<= 1;
  }
  ushortT* h1 = (ushortT*)(ws + off);

  cvt_kernel<<<(1536 * 512 / 4 + 255) / 256, 256, 0, stream>>>(qkv_w, qkvw_b, 1536 * 512 / 4);
  cvt_kernel<<<(512 * 512 / 4 + 255) / 256, 256, 0, stream>>>(proj_w, projw_b, 512 * 512 / 4);
  cvt_kernel<<<(2048 * 512 / 4 + 255) / 256, 256, 0, stream>>>(fc1_w, fc1w_b, 2048 * 512 / 4);
  cvt_kernel<<<(512 * 2048 / 4 + 255) / 256, 256, 0, stream>>>(fc2_w, fc2w_b, 512 * 2048 / 4);

  ln_kernel<false><<<TOK / 4, 256, 0, stream>>>(x, n1g, n1b, bufA);

  gemm256<0><<<dim3(TOK / 256, 1536 / 256), 512, 0, stream>>>(
      bufA, qkvw_b, qkv_b, TOK, 1536, 512, bufQ, nullptr, nullptr, nullptr);

  attn_kernel<<<8192, 512, 0, stream>>>(bufQ, bufA);

  gemm256<1><<<dim3(TOK / 256, 512 / 256), 512, 0, stream>>>(
      bufA, projw_b, proj_b, TOK, 512, 512, x1, nullptr, x, nullptr);

  ln_kernel<true><<<TOK / 4, 256, 0, stream>>>(x1, n2g, n2b, bufA);

  const int tc = TOK / nch;
  for (int c = 0; c < nch; ++c) {
    const ushortT* hin = bufA + (size_t)c * tc * 512;
    gemm256<2><<<dim3(tc / 256, 2048 / 256), 512, 0, stream>>>(
        hin, fc1w_b, fc1_b, tc, 2048, 512, h1, nullptr, nullptr, nullptr);
    gemm256<3><<<dim3(tc / 256, 512 / 256), 512, 0, stream>>>(
        h1, fc2w_b, fc2_b, tc, 512, 2048, nullptr, out + (size_t)c * tc * 512,
        nullptr, x1 + (size_t)c * tc * 512);
  }
}